// Round 9
// baseline (71.456 us; speedup 1.0000x reference)
//
#include <hip/hip_runtime.h>

// SSIM loss, fused. in: f32 (16,3,512,512) x2; out: f32[16].
//
// 1 wave owns a 512-col x RPS-row strip, 8 cols/lane. Vertical sliding
// 11-row column sums {s1,s2,sp=sum(x1*x2),sq=sum(x1^2+x2^2)} in REGISTERS.
// Per output row: 8x ds_write_b128 of own col-quads into sigma-permuted
// wave-private LDS (sigma(8t+i)=i*64+t: writes AND halo reads conflict-free),
// 10x ds_read_b128 halo; window slide uses own sums from registers. No
// __syncthreads anywhere (wave-private LDS + lgkmcnt).
//
// Round-9 changes (r8 was latency-bound: 26% occupancy, 25% VALUBusy,
// no pipe saturated):
//  * WPB=2 (128-thr blocks): 2016 blocks @ RPS=6 -> ~7.9 blocks/CU vs the
//    8-block VGPR cap -> ~16 waves/CU resident (2x r8).
//  * 4-deep global pipeline: 2 NEW + 2 OLD row buffers, prefetch distance
//    2 iterations (~1000cy) -> ~16KB in flight per wave (2x r8).
//  * VGPR budget ~120 (<128 cliff). Spill check: WRITE_SIZE ~ 0.

namespace {
constexpr int BATCH = 16;
constexpr int CHAN  = 3;
constexpr int HDIM  = 512;
constexpr int WDIM  = 512;
constexpr int WIN   = 11;
constexpr int HO    = HDIM - WIN + 1;   // 502
constexpr int WO    = WDIM - WIN + 1;   // 502
constexpr int RPS   = 6;
constexpr int STRIPS = (HO + RPS - 1) / RPS;     // 84 (last strip: 4 rows)
constexpr int WPB   = 2;                          // waves per block
constexpr int NTHR  = WPB * 64;                   // 128
constexpr int NWAVE = BATCH * CHAN * STRIPS;      // 4032
constexpr int NBLK  = NWAVE / WPB;                // 2016
constexpr int NBANK = 16;                         // atomic banks per image
// scale-folded constants: C*121^2 (121^4 cancels in n/d)
constexpr float K1 = 6.5025f  * 14641.0f;
constexpr float K2 = 58.5225f * 14641.0f;
constexpr float W2F = 121.0f;
}

struct RowBuf { float4 u0, u1, v0, v1; };

__global__ __launch_bounds__(NTHR) void ssim_main(
    const float* __restrict__ g1, const float* __restrict__ g2,
    double* __restrict__ ws) {
  __shared__ float4 lds4[WPB * 512];               // 16 KB

  const int t   = threadIdx.x & 63;
  const int wv  = threadIdx.x >> 6;
  const int wid = blockIdx.x * WPB + wv;
  const int img   = wid / STRIPS;        // (b,c) pair, 0..47
  const int strip = wid % STRIPS;
  const int b   = img / CHAN;
  const int r0  = strip * RPS;
  const int r1  = min(r0 + RPS, HO);

  const int cb = 8 * t;                  // first owned col
  float4* __restrict__ W  = lds4 + wv * 512;
  const float4* __restrict__ Rd = lds4 + wv * 512;
  const int tp1 = (t + 1) & 63;          // halo lanes (wrap -> masked outputs)
  const int tp2 = (t + 2) & 63;

  const float* __restrict__ p1 = g1 + (size_t)img * HDIM * WDIM + cb;
  const float* __restrict__ p2 = g2 + (size_t)img * HDIM * WDIM + cb;

  // vertical sliding column sums for the lane's own 8 columns
  float s1[8], s2[8], sp[8], sq[8];
#pragma unroll
  for (int k = 0; k < 8; ++k) s1[k] = s2[k] = sp[k] = sq[k] = 0.f;

  RowBuf A0, A1, B0, B1;                 // 4-deep rotation
  auto load = [&](RowBuf& R, int row) {
    const float* q1 = p1 + (size_t)row * WDIM;
    const float* q2 = p2 + (size_t)row * WDIM;
    R.u0 = *(const float4*)q1; R.u1 = *(const float4*)(q1 + 4);
    R.v0 = *(const float4*)q2; R.v1 = *(const float4*)(q2 + 4);
  };
  auto accum = [&](const RowBuf& R) {
    float uu[8] = {R.u0.x, R.u0.y, R.u0.z, R.u0.w, R.u1.x, R.u1.y, R.u1.z, R.u1.w};
    float vv[8] = {R.v0.x, R.v0.y, R.v0.z, R.v0.w, R.v1.x, R.v1.y, R.v1.z, R.v1.w};
#pragma unroll
    for (int k = 0; k < 8; ++k) {
      float x = uu[k], y = vv[k];
      s1[k] += x;
      s2[k] += y;
      sp[k] = fmaf(x, y, sp[k]);
      sq[k] = fmaf(x, x, sq[k]);
      sq[k] = fmaf(y, y, sq[k]);
    }
  };
  auto desum = [&](const RowBuf& R) {
    float uu[8] = {R.u0.x, R.u0.y, R.u0.z, R.u0.w, R.u1.x, R.u1.y, R.u1.z, R.u1.w};
    float vv[8] = {R.v0.x, R.v0.y, R.v0.z, R.v0.w, R.v1.x, R.v1.y, R.v1.z, R.v1.w};
#pragma unroll
    for (int k = 0; k < 8; ++k) {
      float x = uu[k], y = vv[k];
      s1[k] -= x;
      s2[k] -= y;
      sp[k] = fmaf(x, -y, sp[k]);
      sq[k] = fmaf(x, -x, sq[k]);
      sq[k] = fmaf(y, -y, sq[k]);
    }
  };

  float acc = 0.f;

  // one output row: NB holds row r+10, OB holds row r; reloads keep the
  // 2-iteration prefetch distance (NB <- r+12, OB <- r+2).
  auto STEP = [&](int r, RowBuf& NB, RowBuf& OB) {
    accum(NB);                               // window = rows [r, r+10]
    load(NB, min(r + 12, HDIM - 1));         // NEW for iter r+2

    // publish own 8 col-quads (consecutive lanes -> contiguous: no conflicts)
#pragma unroll
    for (int i = 0; i < 8; ++i)
      W[i * 64 + t] = make_float4(s1[i], s2[i], sp[i], sq[i]);
    asm volatile("s_waitcnt lgkmcnt(0)" ::: "memory");

    // halo: cols cb+8+m. m<8: quad m*64+(t+1); m=8,9: (m-8)*64+(t+2)
    float4 cN[10];
#pragma unroll
    for (int m = 0; m < 8; ++m) cN[m] = Rd[m * 64 + tp1];
    cN[8] = Rd[tp2];
    cN[9] = Rd[64 + tp2];

    float w1 = ((s1[0] + s1[1]) + (s1[2] + s1[3])) +
               ((s1[4] + s1[5]) + (s1[6] + s1[7])) +
               ((cN[0].x + cN[1].x) + cN[2].x);
    float w2 = ((s2[0] + s2[1]) + (s2[2] + s2[3])) +
               ((s2[4] + s2[5]) + (s2[6] + s2[7])) +
               ((cN[0].y + cN[1].y) + cN[2].y);
    float wp = ((sp[0] + sp[1]) + (sp[2] + sp[3])) +
               ((sp[4] + sp[5]) + (sp[6] + sp[7])) +
               ((cN[0].z + cN[1].z) + cN[2].z);
    float wq = ((sq[0] + sq[1]) + (sq[2] + sq[3])) +
               ((sq[4] + sq[5]) + (sq[6] + sq[7])) +
               ((cN[0].w + cN[1].w) + cN[2].w);

#pragma unroll
    for (int j = 0; j < 8; ++j) {
      if (j > 0) {
        w1 = (w1 - s1[j - 1]) + cN[j + 2].x;
        w2 = (w2 - s2[j - 1]) + cN[j + 2].y;
        wp = (wp - sp[j - 1]) + cN[j + 2].z;
        wq = (wq - sq[j - 1]) + cN[j + 2].w;
      }
      // scale-folded SSIM (121^4 cancels in n/d)
      float s12 = w1 * w2;
      float msq = fmaf(w1, w1, w2 * w2);
      float N1  = fmaf(2.f, s12, K1);
      float N2  = fmaf(2.f, fmaf(W2F, wp, -s12), K2);
      float D1  = msq + K1;
      float D2  = fmaf(W2F, wq, -msq) + K2;
      float val = (N1 * N2) * __builtin_amdgcn_rcpf(D1 * D2);
      acc += (cb + j < WO) ? val : 0.f;
    }

    desum(OB);                               // remove row r from sums
    load(OB, min(r + 2, HDIM - 1));          // OLD for iter r+2 (L2/L3 hit)
  };

  // ---- warm-up: accumulate rows r0..r0+9, 4-deep pipelined; end state:
  //      B0 = row r0+10, B1 = r0+11 (NEW);  A0 = r0, A1 = r0+1 (OLD) ----
  load(A0, r0);     load(A1, r0 + 1);
  load(B0, r0 + 2); load(B1, r0 + 3);
  accum(A0);  load(A0, r0 + 4);
  accum(A1);  load(A1, r0 + 5);
  accum(B0);  load(B0, r0 + 6);
  accum(B1);  load(B1, r0 + 7);
  accum(A0);  load(A0, r0 + 8);
  accum(A1);  load(A1, r0 + 9);
  accum(B0);  load(B0, r0 + 10);
  accum(B1);  load(B1, min(r0 + 11, HDIM - 1));
  accum(A0);  load(A0, r0);                  // reload as OLD
  accum(A1);  load(A1, r0 + 1);

  // ---- main loop: even rows use (B0,A0), odd rows (B1,A1) ----
  for (int ii = 0; ii < RPS / 2; ++ii) {
    int r = r0 + 2 * ii;
    if (r < r1)     STEP(r,     B0, A0);
    if (r + 1 < r1) STEP(r + 1, B1, A1);
  }

  // wave reduction (cold), banked double atomic
#pragma unroll
  for (int off = 32; off > 0; off >>= 1) acc += __shfl_down(acc, off, 64);
  if (t == 0) atomicAdd(&ws[b * NBANK + (wid & (NBANK - 1))], (double)acc);
}

__global__ void ssim_finalize(const double* __restrict__ ws,
                              float* __restrict__ out) {
  int i = threadIdx.x;
  if (i < BATCH) {
    double s = 0.0;
#pragma unroll
    for (int k = 0; k < NBANK; ++k) s += ws[i * NBANK + k];
    out[i] = (float)(1.0 - s / ((double)CHAN * HO * WO));
  }
}

extern "C" void kernel_launch(void* const* d_in, const int* in_sizes, int n_in,
                              void* d_out, int out_size, void* d_ws,
                              size_t ws_size, hipStream_t stream) {
  const float* img1 = (const float*)d_in[0];
  const float* img2 = (const float*)d_in[1];
  float* out = (float*)d_out;
  double* ws = (double*)d_ws;

  hipMemsetAsync(d_ws, 0, BATCH * NBANK * sizeof(double), stream);
  ssim_main<<<dim3(NBLK), NTHR, 0, stream>>>(img1, img2, ws);
  ssim_finalize<<<1, 64, 0, stream>>>(ws, out);
}

// Round 10
// 51.064 us; speedup vs baseline: 1.3993x; 1.3993x over previous
//
#include <hip/hip_runtime.h>

// SSIM loss, fused. in: f32 (16,3,512,512) x2; out: f32[16].
//
// r8 structure (best so far: 62us) + XCD-image-clustered block swizzle.
// 1 wave owns a 512-col x RPS-row strip, 8 cols/lane. Vertical sliding
// 11-row column sums {s1,s2,sp,sq} in registers; per output row publish own
// col-quads to sigma-permuted wave-private LDS (8x ds_write_b128,
// conflict-free), read 10 halo quads (b128), slide window using own sums
// from registers. No __syncthreads. NEW row prefetched one iter ahead;
// OLD row re-read (L2/L3). Banked double atomics.
//
// r10 change: bijective XCD clustering. blockIdx = xcd + 8*(sblk + g*26),
// img = g*8 + xcd. All 26 blocks of an image land on one XCD (dispatch
// round-robins XCD by blockIdx%8), images serialized per XCD -> per-XCD L2
// working set ~6 images (12MB) instead of 48 (96MB) -> halo/OLD re-reads
// hit L2. Readout: FETCH_SIZE (L2-fill) 168MB -> target <140MB.

namespace {
constexpr int BATCH = 16;
constexpr int CHAN  = 3;
constexpr int HDIM  = 512;
constexpr int WDIM  = 512;
constexpr int WIN   = 11;
constexpr int HO    = HDIM - WIN + 1;   // 502
constexpr int WO    = WDIM - WIN + 1;   // 502
constexpr int RPS   = 5;
constexpr int STRIPS = (HO + RPS - 1) / RPS;     // 101 real strips
constexpr int WPB   = 4;                          // waves per block
constexpr int NTHR  = WPB * 64;
constexpr int SBLK  = (STRIPS + WPB - 1) / WPB;   // 26 strip-blocks per image
constexpr int NIMG  = BATCH * CHAN;               // 48
constexpr int NXCD  = 8;
constexpr int GRP   = NIMG / NXCD;                // 6 images per XCD
constexpr int NBLK  = NIMG * SBLK;                // 1248
constexpr int NBANK = 16;
// scale-folded constants: C*121^2 (121^4 cancels in n/d)
constexpr float K1 = 6.5025f  * 14641.0f;
constexpr float K2 = 58.5225f * 14641.0f;
constexpr float W2F = 121.0f;
}

__global__ __launch_bounds__(NTHR) void ssim_main(
    const float* __restrict__ g1, const float* __restrict__ g2,
    double* __restrict__ ws) {
  __shared__ float4 lds4[WPB * 512];               // 32 KB

  const int t   = threadIdx.x & 63;
  const int wv  = threadIdx.x >> 6;

  // XCD-clustered decode: xcd = img%8; within an XCD, images serialize.
  const int xcd  = blockIdx.x & (NXCD - 1);
  const int q    = blockIdx.x >> 3;        // 0 .. GRP*SBLK-1
  const int g    = q / SBLK;
  const int sblk = q % SBLK;
  const int img  = g * NXCD + xcd;         // 0..47
  const int strip = sblk * WPB + wv;
  if (strip >= STRIPS) return;             // 3 pad waves per image

  const int b   = img / CHAN;
  const int r0  = strip * RPS;
  const int r1  = min(r0 + RPS, HO);

  const int cb = 8 * t;                    // first owned col
  float4* __restrict__ W  = lds4 + wv * 512;
  const float4* __restrict__ Rd = lds4 + wv * 512;
  const int tp1 = (t + 1) & 63;            // halo lanes (wrap -> masked cols)
  const int tp2 = (t + 2) & 63;

  const float* __restrict__ p1 = g1 + (size_t)img * HDIM * WDIM + cb;
  const float* __restrict__ p2 = g2 + (size_t)img * HDIM * WDIM + cb;

  float s1[8], s2[8], sp[8], sq[8];
#pragma unroll
  for (int k = 0; k < 8; ++k) s1[k] = s2[k] = sp[k] = sq[k] = 0.f;

  float4 au0, au1, av0, av1, bu0, bu1, bv0, bv1;
  auto loadA = [&](int row) {
    const float* q1 = p1 + (size_t)row * WDIM;
    const float* q2 = p2 + (size_t)row * WDIM;
    au0 = *(const float4*)q1; au1 = *(const float4*)(q1 + 4);
    av0 = *(const float4*)q2; av1 = *(const float4*)(q2 + 4);
  };
  auto loadB = [&](int row) {
    const float* q1 = p1 + (size_t)row * WDIM;
    const float* q2 = p2 + (size_t)row * WDIM;
    bu0 = *(const float4*)q1; bu1 = *(const float4*)(q1 + 4);
    bv0 = *(const float4*)q2; bv1 = *(const float4*)(q2 + 4);
  };
  auto accum = [&]() {
    float uu[8] = {au0.x, au0.y, au0.z, au0.w, au1.x, au1.y, au1.z, au1.w};
    float vv[8] = {av0.x, av0.y, av0.z, av0.w, av1.x, av1.y, av1.z, av1.w};
#pragma unroll
    for (int k = 0; k < 8; ++k) {
      float x = uu[k], y = vv[k];
      s1[k] += x;
      s2[k] += y;
      sp[k] = fmaf(x, y, sp[k]);
      sq[k] = fmaf(x, x, sq[k]);
      sq[k] = fmaf(y, y, sq[k]);
    }
  };
  auto desum = [&]() {
    float uu[8] = {bu0.x, bu0.y, bu0.z, bu0.w, bu1.x, bu1.y, bu1.z, bu1.w};
    float vv[8] = {bv0.x, bv0.y, bv0.z, bv0.w, bv1.x, bv1.y, bv1.z, bv1.w};
#pragma unroll
    for (int k = 0; k < 8; ++k) {
      float x = uu[k], y = vv[k];
      s1[k] -= x;
      s2[k] -= y;
      sp[k] = fmaf(x, -y, sp[k]);
      sq[k] = fmaf(x, -x, sq[k]);
      sq[k] = fmaf(y, -y, sq[k]);
    }
  };

  // ---- warm-up: accumulate rows r0 .. r0+9, 2-deep pipelined ----
  loadA(r0);
  loadB(r0 + 1);
#pragma unroll
  for (int dy = 0; dy < 10; dy += 2) {
    accum();
    loadA(r0 + dy + 2);      // dy=8 -> loads row r0+10 = first NEW
    { float4 tu0 = au0, tu1 = au1, tv0 = av0, tv1 = av1;
      au0 = bu0; au1 = bu1; av0 = bv0; av1 = bv1;
      accum();
      au0 = tu0; au1 = tu1; av0 = tv0; av1 = tv1; }
    if (dy < 8) loadB(r0 + dy + 3);
  }
  loadB(r0);                 // first OLD row

  // ---- main loop ----
  float acc = 0.f;
  for (int r = r0; r < r1; ++r) {
    accum();                              // window = rows [r, r+10]
    loadA(min(r + WIN, HDIM - 1));        // prefetch next NEW

    // publish own 8 col-quads (consecutive lanes contiguous: conflict-free)
#pragma unroll
    for (int i = 0; i < 8; ++i)
      W[i * 64 + t] = make_float4(s1[i], s2[i], sp[i], sq[i]);
    asm volatile("s_waitcnt lgkmcnt(0)" ::: "memory");

    // halo: cols cb+8+m. m<8: quad m*64+(t+1); m=8,9: (m-8)*64+(t+2)
    float4 cN[10];
#pragma unroll
    for (int m = 0; m < 8; ++m) cN[m] = Rd[m * 64 + tp1];
    cN[8] = Rd[tp2];
    cN[9] = Rd[64 + tp2];

    float w1 = ((s1[0] + s1[1]) + (s1[2] + s1[3])) +
               ((s1[4] + s1[5]) + (s1[6] + s1[7])) +
               ((cN[0].x + cN[1].x) + cN[2].x);
    float w2 = ((s2[0] + s2[1]) + (s2[2] + s2[3])) +
               ((s2[4] + s2[5]) + (s2[6] + s2[7])) +
               ((cN[0].y + cN[1].y) + cN[2].y);
    float wp = ((sp[0] + sp[1]) + (sp[2] + sp[3])) +
               ((sp[4] + sp[5]) + (sp[6] + sp[7])) +
               ((cN[0].z + cN[1].z) + cN[2].z);
    float wq = ((sq[0] + sq[1]) + (sq[2] + sq[3])) +
               ((sq[4] + sq[5]) + (sq[6] + sq[7])) +
               ((cN[0].w + cN[1].w) + cN[2].w);

#pragma unroll
    for (int j = 0; j < 8; ++j) {
      if (j > 0) {
        w1 = (w1 - s1[j - 1]) + cN[j + 2].x;
        w2 = (w2 - s2[j - 1]) + cN[j + 2].y;
        wp = (wp - sp[j - 1]) + cN[j + 2].z;
        wq = (wq - sq[j - 1]) + cN[j + 2].w;
      }
      // scale-folded SSIM (121^4 cancels in n/d)
      float s12 = w1 * w2;
      float msq = fmaf(w1, w1, w2 * w2);
      float N1  = fmaf(2.f, s12, K1);
      float N2  = fmaf(2.f, fmaf(W2F, wp, -s12), K2);
      float D1  = msq + K1;
      float D2  = fmaf(W2F, wq, -msq) + K2;
      float val = (N1 * N2) * __builtin_amdgcn_rcpf(D1 * D2);
      acc += (cb + j < WO) ? val : 0.f;
    }

    desum();                              // slide out row r
    loadB(r + 1);                         // prefetch next OLD (L2 hit now)
  }

  // wave reduction (cold), banked double atomic
#pragma unroll
  for (int off = 32; off > 0; off >>= 1) acc += __shfl_down(acc, off, 64);
  if (t == 0) {
    int bank = (img * STRIPS + strip) & (NBANK - 1);
    atomicAdd(&ws[b * NBANK + bank], (double)acc);
  }
}

__global__ void ssim_finalize(const double* __restrict__ ws,
                              float* __restrict__ out) {
  int i = threadIdx.x;
  if (i < BATCH) {
    double s = 0.0;
#pragma unroll
    for (int k = 0; k < NBANK; ++k) s += ws[i * NBANK + k];
    out[i] = (float)(1.0 - s / ((double)CHAN * HO * WO));
  }
}

extern "C" void kernel_launch(void* const* d_in, const int* in_sizes, int n_in,
                              void* d_out, int out_size, void* d_ws,
                              size_t ws_size, hipStream_t stream) {
  const float* img1 = (const float*)d_in[0];
  const float* img2 = (const float*)d_in[1];
  float* out = (float*)d_out;
  double* ws = (double*)d_ws;

  hipMemsetAsync(d_ws, 0, BATCH * NBANK * sizeof(double), stream);
  ssim_main<<<dim3(NBLK), NTHR, 0, stream>>>(img1, img2, ws);
  ssim_finalize<<<1, 64, 0, stream>>>(ws, out);
}